// Round 16
// baseline (199.827 us; speedup 1.0000x reference)
//
#include <hip/hip_runtime.h>
#include <hip/hip_bf16.h>

// Windowed MHA, B=16 C=128 H=W=128, WINDOW=64, heads=4, d=32.
// R16 = R15 pipeline, TWO windows per block (grid 2048):
//   prefetch both windows' X to regs -> write both LDS buffers (32KB) ->
//   ONE barrier -> per-wave R15 pipeline on window A, then window B
//   (B: zero exposed load latency, weights hot in L1/L2).
// #pragma unroll 1 on the window loop stops weight-load hoisting (VGPR control).

typedef __attribute__((ext_vector_type(8))) short bf16x8;
typedef __attribute__((ext_vector_type(4))) float f32x4;

__device__ __forceinline__ ushort f2bf(float f) {
    __hip_bfloat16 h = __float2bfloat16(f);       // RNE
    ushort u; __builtin_memcpy(&u, &h, 2); return u;
}
__device__ __forceinline__ unsigned pk2(float a, float b) {
    __hip_bfloat162 h = __float22bfloat162_rn(make_float2(a, b));  // lo=a, hi=b
    unsigned u; __builtin_memcpy(&u, &h, 4); return u;
}
// 256B-row tile (sX): row bits 0-3 ^ bits 4-5 -> byte bits 4-7.
__device__ __forceinline__ int fsw(int row) { return ((row ^ (row >> 4)) & 15) << 4; }

__global__ void wconv(const float* __restrict__ Wq, const float* __restrict__ Wk,
                      const float* __restrict__ Wv, ushort* __restrict__ out) {
    int i = blockIdx.x * 256 + threadIdx.x;        // 16384 per matrix
    out[i]         = f2bf(Wq[i]);
    out[16384 + i] = f2bf(Wk[i]);
    out[32768 + i] = f2bf(Wv[i]);
}

__global__ __launch_bounds__(256, 2)
void attn_win(const float* __restrict__ x, const ushort* __restrict__ wbf,
              const float* __restrict__ bq, const float* __restrict__ bk,
              const float* __restrict__ bv, const float* __restrict__ Bb,
              float* __restrict__ out) {
    __shared__ __align__(16) char sX[2][16384];

    const int tid = threadIdx.x;
    const int w = tid >> 6;          // wave = head (0..3)
    const int l = tid & 63;
    const int lr = l & 15;
    const int lg = (l >> 4) & 3;
    const int blk = blockIdx.x;      // 2048 blocks; windows 2blk, 2blk+1
    const int gw0 = 2 * blk;
    const long xbase0 = (long)(gw0 >> 8) * 128 * 16384 + (long)(gw0 & 255) * 64;
    // window wi base: gw = gw0 + wi; same b (gw0&255 <= 254), so base0 + wi*64
    // (2blk and 2blk+1 share b since 2blk&255 is even, +1 stays in [0,255])

    // shfl lane plumbing (R5/R12/R13-proven)
    const int s0 = 32 * (lg & 1) + lr;
    const int s1 = s0 + 16;
    const bool hi2 = (lg >> 1);

    // ---- prefetch BOTH windows' X into registers, then stage both buffers ----
    {
        float4 pf[2][2][4];
        #pragma unroll
        for (int wi = 0; wi < 2; ++wi)
            #pragma unroll
            for (int it = 0; it < 2; ++it) {
                int idx = it * 256 + tid;            // 512 items: 32 cq x 16 t4
                int cq = idx >> 4, t4 = idx & 15;
                const float* px = x + xbase0 + wi * 64 + (long)(4 * cq) * 16384 + t4 * 4;
                pf[wi][it][0] = *(const float4*)(px);
                pf[wi][it][1] = *(const float4*)(px + 16384);
                pf[wi][it][2] = *(const float4*)(px + 32768);
                pf[wi][it][3] = *(const float4*)(px + 49152);
            }
        #pragma unroll
        for (int wi = 0; wi < 2; ++wi)
            #pragma unroll
            for (int it = 0; it < 2; ++it) {
                int idx = it * 256 + tid;
                int cq = idx >> 4, t4 = idx & 15;
                float a0[4] = {pf[wi][it][0].x, pf[wi][it][0].y, pf[wi][it][0].z, pf[wi][it][0].w};
                float a1[4] = {pf[wi][it][1].x, pf[wi][it][1].y, pf[wi][it][1].z, pf[wi][it][1].w};
                float a2[4] = {pf[wi][it][2].x, pf[wi][it][2].y, pf[wi][it][2].z, pf[wi][it][2].w};
                float a3[4] = {pf[wi][it][3].x, pf[wi][it][3].y, pf[wi][it][3].z, pf[wi][it][3].w};
                #pragma unroll
                for (int jj = 0; jj < 4; ++jj) {
                    int t = t4 * 4 + jj;
                    uint2 pk;
                    pk.x = pk2(a0[jj], a1[jj]);
                    pk.y = pk2(a2[jj], a3[jj]);
                    *(uint2*)(&sX[wi][0] + t * 256 + ((8 * cq) ^ fsw(t))) = pk;
                }
            }
    }
    __syncthreads();   // THE ONLY BARRIER

    #pragma unroll 1
    for (int wi = 0; wi < 2; ++wi) {
        const char* sXw = &sX[wi][0];
        const long xb = xbase0 + wi * 64;

        // ---- Q,K projections FUSED (W.X^T): shared aXk, 16 indep accumulators ----
        bf16x8 fQ[4], fK[4];
        {
            f32x4 accQ[2][4], accK[2][4];   // [tn och-tile][tm tok-tile]
            #pragma unroll
            for (int tn = 0; tn < 2; ++tn) {
                float4 bbq = *(const float4*)(bq + 32 * w + 16 * tn + 4 * lg);
                float4 bbk = *(const float4*)(bk + 32 * w + 16 * tn + 4 * lg);
                #pragma unroll
                for (int tm = 0; tm < 4; ++tm) {
                    accQ[tn][tm] = (f32x4){bbq.x, bbq.y, bbq.z, bbq.w};
                    accK[tn][tm] = (f32x4){bbk.x, bbk.y, bbk.z, bbk.w};
                }
            }
            #pragma unroll
            for (int kk = 0; kk < 4; ++kk) {
                bf16x8 aXk[4];
                #pragma unroll
                for (int tm = 0; tm < 4; ++tm) {
                    int row = 16 * tm + lr;
                    aXk[tm] = *(const bf16x8*)(sXw + row * 256
                                  + (((8 * lg + 32 * kk) * 2) ^ fsw(row)));
                }
                bf16x8 bWq[2], bWk[2];
                #pragma unroll
                for (int tn = 0; tn < 2; ++tn) {
                    int orow = (32 * w + 16 * tn + lr) * 128 + 8 * lg + 32 * kk;
                    bWq[tn] = *(const bf16x8*)(wbf + orow);
                    bWk[tn] = *(const bf16x8*)(wbf + 16384 + orow);
                }
                #pragma unroll
                for (int tn = 0; tn < 2; ++tn)
                    #pragma unroll
                    for (int tm = 0; tm < 4; ++tm) {
                        accQ[tn][tm] = __builtin_amdgcn_mfma_f32_16x16x32_bf16(
                            bWq[tn], aXk[tm], accQ[tn][tm], 0, 0, 0);
                        accK[tn][tm] = __builtin_amdgcn_mfma_f32_16x16x32_bf16(
                            bWk[tn], aXk[tm], accK[tn][tm], 0, 0, 0);
                    }
            }
            #pragma unroll
            for (int p = 0; p < 2; ++p) {
                unsigned qpk[4][2][2];
                #pragma unroll
                for (int tm = 0; tm < 4; ++tm)
                    #pragma unroll
                    for (int tn = 0; tn < 2; ++tn) {
                        const f32x4& a = (p == 0) ? accQ[tn][tm] : accK[tn][tm];
                        qpk[tm][tn][0] = pk2(a[0], a[1]);
                        qpk[tm][tn][1] = pk2(a[2], a[3]);
                    }
                #pragma unroll
                for (int tm = 0; tm < 4; ++tm) {
                    int t00 = __shfl((int)qpk[tm][0][0], s0);
                    int t01 = __shfl((int)qpk[tm][0][1], s0);
                    int t10 = __shfl((int)qpk[tm][1][0], s0);
                    int t11 = __shfl((int)qpk[tm][1][1], s0);
                    int u00 = __shfl((int)qpk[tm][0][0], s1);
                    int u01 = __shfl((int)qpk[tm][0][1], s1);
                    int u10 = __shfl((int)qpk[tm][1][0], s1);
                    int u11 = __shfl((int)qpk[tm][1][1], s1);
                    int4 wv;
                    wv.x = hi2 ? t10 : t00;
                    wv.y = hi2 ? t11 : t01;
                    wv.z = hi2 ? u10 : u00;
                    wv.w = hi2 ? u11 : u01;
                    if (p == 0) fQ[tm] = *(bf16x8*)&wv;
                    else        fK[tm] = *(bf16x8*)&wv;
                }
            }
        }

        // ---- V projection (X.W^T): D[tok][och] -> shfl -> PV B-fragments ----
        bf16x8 fV[2][2];   // [kk2][tn]
        {
            const ushort* wp = wbf + 32768;
            f32x4 acc[4][2];
            #pragma unroll
            for (int tn = 0; tn < 2; ++tn) {
                float bias = bv[32 * w + 16 * tn + lr];
                #pragma unroll
                for (int tmi = 0; tmi < 4; ++tmi)
                    acc[tmi][tn] = (f32x4){bias, bias, bias, bias};
            }
            #pragma unroll
            for (int kk = 0; kk < 4; ++kk) {
                bf16x8 aXk[4];
                #pragma unroll
                for (int tmi = 0; tmi < 4; ++tmi) {
                    int row = 16 * tmi + lr;
                    aXk[tmi] = *(const bf16x8*)(sXw + row * 256
                                   + (((8 * lg + 32 * kk) * 2) ^ fsw(row)));
                }
                bf16x8 bW[2];
                #pragma unroll
                for (int tn = 0; tn < 2; ++tn)
                    bW[tn] = *(const bf16x8*)(wp + (32 * w + 16 * tn + lr) * 128 + 8 * lg + 32 * kk);
                #pragma unroll
                for (int tmi = 0; tmi < 4; ++tmi)
                    #pragma unroll
                    for (int tn = 0; tn < 2; ++tn)
                        acc[tmi][tn] = __builtin_amdgcn_mfma_f32_16x16x32_bf16(
                            aXk[tmi], bW[tn], acc[tmi][tn], 0, 0, 0);
            }
            unsigned vpk[4][2][2];
            #pragma unroll
            for (int tmi = 0; tmi < 4; ++tmi)
                #pragma unroll
                for (int tn = 0; tn < 2; ++tn) {
                    vpk[tmi][tn][0] = pk2(acc[tmi][tn][0], acc[tmi][tn][1]);
                    vpk[tmi][tn][1] = pk2(acc[tmi][tn][2], acc[tmi][tn][3]);
                }
            #pragma unroll
            for (int kk2 = 0; kk2 < 2; ++kk2)
                #pragma unroll
                for (int tn = 0; tn < 2; ++tn) {
                    int tmA = 2 * kk2, tmB = 2 * kk2 + 1;
                    int a0 = __shfl((int)vpk[tmA][tn][0], s0);
                    int a1 = __shfl((int)vpk[tmA][tn][1], s0);
                    int a2 = __shfl((int)vpk[tmA][tn][0], s1);
                    int a3 = __shfl((int)vpk[tmA][tn][1], s1);
                    int b0 = __shfl((int)vpk[tmB][tn][0], s0);
                    int b1 = __shfl((int)vpk[tmB][tn][1], s0);
                    int b2 = __shfl((int)vpk[tmB][tn][0], s1);
                    int b3 = __shfl((int)vpk[tmB][tn][1], s1);
                    int4 wv;
                    wv.x = hi2 ? b0 : a0;
                    wv.y = hi2 ? b1 : a1;
                    wv.z = hi2 ? b2 : a2;
                    wv.w = hi2 ? b3 : a3;
                    fV[kk2][tn] = *(bf16x8*)&wv;
                }
        }

        // ---- scores^T = mfma(A=K, B=Q) ----
        f32x4 sc[4][4];   // [tmK][tmQ]
        #pragma unroll
        for (int tmK = 0; tmK < 4; ++tmK)
            #pragma unroll
            for (int tmQ = 0; tmQ < 4; ++tmQ) {
                sc[tmK][tmQ] = (f32x4){0.f, 0.f, 0.f, 0.f};
                sc[tmK][tmQ] = __builtin_amdgcn_mfma_f32_16x16x32_bf16(
                    fK[tmK], fQ[tmQ], sc[tmK][tmQ], 0, 0, 0);
            }

        // ---- softmax (no max-sub); normalize at source ----
        const float scale = 0.17677669529663687f;   // 1/sqrt(32)
        const float L2E = 1.4426950408889634f;
        #pragma unroll
        for (int tmQ = 0; tmQ < 4; ++tmQ) {
            int q = 16 * tmQ + lr;
            float s = 0.f;
            #pragma unroll
            for (int tmK = 0; tmK < 4; ++tmK) {
                float4 bb = *(const float4*)(Bb + q * 64 + 16 * tmK + 4 * lg);
                float e0 = exp2f((sc[tmK][tmQ][0] * scale + bb.x) * L2E);
                float e1 = exp2f((sc[tmK][tmQ][1] * scale + bb.y) * L2E);
                float e2 = exp2f((sc[tmK][tmQ][2] * scale + bb.z) * L2E);
                float e3 = exp2f((sc[tmK][tmQ][3] * scale + bb.w) * L2E);
                sc[tmK][tmQ][0] = e0; sc[tmK][tmQ][1] = e1;
                sc[tmK][tmQ][2] = e2; sc[tmK][tmQ][3] = e3;
                s += (e0 + e1) + (e2 + e3);
            }
            s += __shfl_xor(s, 16);
            s += __shfl_xor(s, 32);
            float rs = 1.0f / s;
            #pragma unroll
            for (int tmK = 0; tmK < 4; ++tmK)
                #pragma unroll
                for (int r = 0; r < 4; ++r)
                    sc[tmK][tmQ][r] *= rs;
        }

        // ---- P pack + PV (A-frag via shfl, proven) ----
        unsigned pks[4][4][2];
        #pragma unroll
        for (int tmK = 0; tmK < 4; ++tmK)
            #pragma unroll
            for (int tmQ = 0; tmQ < 4; ++tmQ) {
                pks[tmK][tmQ][0] = pk2(sc[tmK][tmQ][0], sc[tmK][tmQ][1]);
                pks[tmK][tmQ][1] = pk2(sc[tmK][tmQ][2], sc[tmK][tmQ][3]);
            }

        f32x4 o[4][2];
        #pragma unroll
        for (int tmq = 0; tmq < 4; ++tmq)
            #pragma unroll
            for (int tn = 0; tn < 2; ++tn)
                o[tmq][tn] = (f32x4){0.f, 0.f, 0.f, 0.f};
        #pragma unroll
        for (int kk2 = 0; kk2 < 2; ++kk2) {
            int tmA = 2 * kk2, tmB = 2 * kk2 + 1;
            #pragma unroll
            for (int tmq = 0; tmq < 4; ++tmq) {
                int a0 = __shfl((int)pks[tmA][tmq][0], s0);
                int b0 = __shfl((int)pks[tmB][tmq][0], s0);
                int a1 = __shfl((int)pks[tmA][tmq][1], s0);
                int b1 = __shfl((int)pks[tmB][tmq][1], s0);
                int a2 = __shfl((int)pks[tmA][tmq][0], s1);
                int b2 = __shfl((int)pks[tmB][tmq][0], s1);
                int a3 = __shfl((int)pks[tmA][tmq][1], s1);
                int b3 = __shfl((int)pks[tmB][tmq][1], s1);
                int4 wv;
                wv.x = hi2 ? b0 : a0;
                wv.y = hi2 ? b1 : a1;
                wv.z = hi2 ? b2 : a2;
                wv.w = hi2 ? b3 : a3;
                bf16x8 aP = *(bf16x8*)&wv;
                #pragma unroll
                for (int tn = 0; tn < 2; ++tn)
                    o[tmq][tn] = __builtin_amdgcn_mfma_f32_16x16x32_bf16(
                        aP, fV[kk2][tn], o[tmq][tn], 0, 0, 0);
            }
        }

        // ---- direct coalesced float4 stores ----
        #pragma unroll
        for (int tmq = 0; tmq < 4; ++tmq)
            #pragma unroll
            for (int tn = 0; tn < 2; ++tn) {
                int ch = 32 * w + 16 * tn + lr;
                int tok = 16 * tmq + 4 * lg;
                float4 ov;
                ov.x = o[tmq][tn][0];
                ov.y = o[tmq][tn][1];
                ov.z = o[tmq][tn][2];
                ov.w = o[tmq][tn][3];
                *(float4*)(out + xb + (long)ch * 16384 + tok) = ov;
            }
    }
}

extern "C" void kernel_launch(void* const* d_in, const int* in_sizes, int n_in,
                              void* d_out, int out_size, void* d_ws, size_t ws_size,
                              hipStream_t stream) {
    const float* x  = (const float*)d_in[0];
    const float* Wq = (const float*)d_in[1];
    const float* bq = (const float*)d_in[2];
    const float* Wk = (const float*)d_in[3];
    const float* bk = (const float*)d_in[4];
    const float* Wv = (const float*)d_in[5];
    const float* bv = (const float*)d_in[6];
    const float* Bb = (const float*)d_in[7];
    float* out = (float*)d_out;
    ushort* wbf = (ushort*)d_ws;   // 3 x 128x128 bf16 = 96 KB

    wconv<<<64, 256, 0, stream>>>(Wq, Wk, Wv, wbf);
    attn_win<<<2048, 256, 0, stream>>>(x, wbf, bq, bk, bv, Bb, out);
}

// Round 17
// 162.542 us; speedup vs baseline: 1.2294x; 1.2294x over previous
//
#include <hip/hip_runtime.h>
#include <hip/hip_bf16.h>

// Windowed MHA, B=16 C=128 H=W=128, WINDOW=64, heads=4, d=32.
// R17: one wave = one (window, head); 4096 x 256thr; ONE barrier.
// ALL matmuls use v_mfma_f32_16x16x16_bf16 (K=16). Key insight: the K=16
// fragment k-mapping (k = 4*(lane>>4)+j) EXACTLY matches the projection
// D-layout (regs = 4 consecutive och/tok), so Q/K/V/P accumulators pack
// in place into the next stage's fragments — zero shfl redistribution
// (R13-R15 spent ~112 bpermute + 56 selects/wave on this).

typedef __attribute__((ext_vector_type(4))) short bf16x4;
typedef __attribute__((ext_vector_type(4))) float f32x4;

#define MFMA16(A, B, C) __builtin_amdgcn_mfma_f32_16x16x16bf16_1k((A), (B), (C), 0, 0, 0)

__device__ __forceinline__ ushort f2bf(float f) {
    __hip_bfloat16 h = __float2bfloat16(f);       // RNE
    ushort u; __builtin_memcpy(&u, &h, 2); return u;
}
__device__ __forceinline__ unsigned pk2(float a, float b) {
    __hip_bfloat162 h = __float22bfloat162_rn(make_float2(a, b));  // lo=a, hi=b
    unsigned u; __builtin_memcpy(&u, &h, 4); return u;
}
__device__ __forceinline__ bf16x4 pk4(float a, float b, float c, float d) {
    uint2 u; u.x = pk2(a, b); u.y = pk2(c, d);
    bf16x4 r; __builtin_memcpy(&r, &u, 8); return r;
}
// 256B-row tile (sX): row bits 0-3 ^ bits 4-5 -> byte bits 4-7.
__device__ __forceinline__ int fsw(int row) { return ((row ^ (row >> 4)) & 15) << 4; }

__global__ void wconv(const float* __restrict__ Wq, const float* __restrict__ Wk,
                      const float* __restrict__ Wv, ushort* __restrict__ out) {
    int i = blockIdx.x * 256 + threadIdx.x;        // 16384 per matrix
    out[i]         = f2bf(Wq[i]);
    out[16384 + i] = f2bf(Wk[i]);
    out[32768 + i] = f2bf(Wv[i]);
}

__global__ __launch_bounds__(256, 2)
void attn_win(const float* __restrict__ x, const ushort* __restrict__ wbf,
              const float* __restrict__ bq, const float* __restrict__ bk,
              const float* __restrict__ bv, const float* __restrict__ Bb,
              float* __restrict__ out) {
    __shared__ __align__(16) char sX[16384];   // the ONLY LDS tenant

    const int tid = threadIdx.x;
    const int w = tid >> 6;          // wave = head (0..3)
    const int l = tid & 63;
    const int lr = l & 15;
    const int lg = (l >> 4) & 3;
    const int blk = blockIdx.x;
    const int b = blk >> 8, n = blk & 255;
    const long xbase = (long)b * 128 * 16384 + n * 64;

    // ---- stage X: 4-channel quads -> packed uint2 ds_writes (2 per thread) ----
    #pragma unroll
    for (int it = 0; it < 2; ++it) {
        int idx = it * 256 + tid;            // 512 items: 32 cq x 16 t4
        int cq = idx >> 4, t4 = idx & 15;
        const float* px = x + xbase + (long)(4 * cq) * 16384 + t4 * 4;
        float4 v0 = *(const float4*)(px);
        float4 v1 = *(const float4*)(px + 16384);
        float4 v2 = *(const float4*)(px + 32768);
        float4 v3 = *(const float4*)(px + 49152);
        float a0[4] = {v0.x, v0.y, v0.z, v0.w};
        float a1[4] = {v1.x, v1.y, v1.z, v1.w};
        float a2[4] = {v2.x, v2.y, v2.z, v2.w};
        float a3[4] = {v3.x, v3.y, v3.z, v3.w};
        #pragma unroll
        for (int jj = 0; jj < 4; ++jj) {
            int t = t4 * 4 + jj;
            uint2 pk;
            pk.x = pk2(a0[jj], a1[jj]);
            pk.y = pk2(a2[jj], a3[jj]);
            *(uint2*)(sX + t * 256 + ((8 * cq) ^ fsw(t))) = pk;
        }
    }
    __syncthreads();   // THE ONLY BARRIER

    // ---- Q,K projections FUSED (W.X^T), K=16 MFMA ----
    // A = W rows (och 32w+16tn+lr, ch 16kk+4lg+j), B = X (tok 16tm+lr, same ch).
    // D[och 4lg+r][tok lr] per (tn,tm) tile.
    f32x4 accQ[2][4], accK[2][4];   // [tn][tm]
    #pragma unroll
    for (int tn = 0; tn < 2; ++tn) {
        float4 bbq = *(const float4*)(bq + 32 * w + 16 * tn + 4 * lg);
        float4 bbk = *(const float4*)(bk + 32 * w + 16 * tn + 4 * lg);
        #pragma unroll
        for (int tm = 0; tm < 4; ++tm) {
            accQ[tn][tm] = (f32x4){bbq.x, bbq.y, bbq.z, bbq.w};
            accK[tn][tm] = (f32x4){bbk.x, bbk.y, bbk.z, bbk.w};
        }
    }
    #pragma unroll
    for (int kk = 0; kk < 8; ++kk) {
        bf16x4 aXk[4];
        #pragma unroll
        for (int tm = 0; tm < 4; ++tm) {
            int row = 16 * tm + lr;
            aXk[tm] = *(const bf16x4*)(sX + row * 256
                          + ((32 * kk + 8 * lg) ^ fsw(row)));
        }
        bf16x4 wq[2], wk[2];
        #pragma unroll
        for (int tn = 0; tn < 2; ++tn) {
            int off = (32 * w + 16 * tn + lr) * 128 + 16 * kk + 4 * lg;
            wq[tn] = *(const bf16x4*)(wbf + off);
            wk[tn] = *(const bf16x4*)(wbf + 16384 + off);
        }
        #pragma unroll
        for (int tn = 0; tn < 2; ++tn)
            #pragma unroll
            for (int tm = 0; tm < 4; ++tm) {
                accQ[tn][tm] = MFMA16(wq[tn], aXk[tm], accQ[tn][tm]);
                accK[tn][tm] = MFMA16(wk[tn], aXk[tm], accK[tn][tm]);
            }
    }
    // pack in place: fragment k-slice tn, lane lr = token, k = och 4lg+j
    bf16x4 fQ[4][2], fK[4][2];   // [tm][tn]
    #pragma unroll
    for (int tm = 0; tm < 4; ++tm)
        #pragma unroll
        for (int tn = 0; tn < 2; ++tn) {
            fQ[tm][tn] = pk4(accQ[tn][tm][0], accQ[tn][tm][1],
                             accQ[tn][tm][2], accQ[tn][tm][3]);
            fK[tm][tn] = pk4(accK[tn][tm][0], accK[tn][tm][1],
                             accK[tn][tm][2], accK[tn][tm][3]);
        }

    // ---- V projection (X.W^T), K=16: A = X (tok rows), B = W (och cols) ----
    // D[tok 4lg+r][och lr] per (tmi,tn) -> directly the PV B-fragment.
    bf16x4 fV[4][2];   // [tmi key-slice][tn]
    {
        const ushort* wp = wbf + 32768;
        f32x4 accV[4][2];
        #pragma unroll
        for (int tn = 0; tn < 2; ++tn) {
            float bias = bv[32 * w + 16 * tn + lr];
            #pragma unroll
            for (int tmi = 0; tmi < 4; ++tmi)
                accV[tmi][tn] = (f32x4){bias, bias, bias, bias};
        }
        #pragma unroll
        for (int kk = 0; kk < 8; ++kk) {
            bf16x4 aXk[4];
            #pragma unroll
            for (int tmi = 0; tmi < 4; ++tmi) {
                int row = 16 * tmi + lr;
                aXk[tmi] = *(const bf16x4*)(sX + row * 256
                               + ((32 * kk + 8 * lg) ^ fsw(row)));
            }
            bf16x4 wv[2];
            #pragma unroll
            for (int tn = 0; tn < 2; ++tn)
                wv[tn] = *(const bf16x4*)(wp + (32 * w + 16 * tn + lr) * 128 + 16 * kk + 4 * lg);
            #pragma unroll
            for (int tmi = 0; tmi < 4; ++tmi)
                #pragma unroll
                for (int tn = 0; tn < 2; ++tn)
                    accV[tmi][tn] = MFMA16(aXk[tmi], wv[tn], accV[tmi][tn]);
        }
        #pragma unroll
        for (int tmi = 0; tmi < 4; ++tmi)
            #pragma unroll
            for (int tn = 0; tn < 2; ++tn)
                fV[tmi][tn] = pk4(accV[tmi][tn][0], accV[tmi][tn][1],
                                  accV[tmi][tn][2], accV[tmi][tn][3]);
    }

    // ---- per-tmQ column: scores^T = mfma(A=fK, B=fQ) -> softmax -> pack P ----
    // D[k 16tmK+4lg+r][q 16tmQ+lr]; P pack is directly the PV A-fragment.
    const float scale = 0.17677669529663687f;   // 1/sqrt(32)
    const float L2E = 1.4426950408889634f;
    bf16x4 pP[4][4];   // [tmK][tmQ]
    #pragma unroll
    for (int tmQ = 0; tmQ < 4; ++tmQ) {
        f32x4 sc[4];
        #pragma unroll
        for (int tmK = 0; tmK < 4; ++tmK) {
            sc[tmK] = (f32x4){0.f, 0.f, 0.f, 0.f};
            sc[tmK] = MFMA16(fK[tmK][0], fQ[tmQ][0], sc[tmK]);
            sc[tmK] = MFMA16(fK[tmK][1], fQ[tmQ][1], sc[tmK]);
        }
        int q = 16 * tmQ + lr;
        float s = 0.f;
        #pragma unroll
        for (int tmK = 0; tmK < 4; ++tmK) {
            float4 bb = *(const float4*)(Bb + q * 64 + 16 * tmK + 4 * lg);
            float e0 = exp2f((sc[tmK][0] * scale + bb.x) * L2E);
            float e1 = exp2f((sc[tmK][1] * scale + bb.y) * L2E);
            float e2 = exp2f((sc[tmK][2] * scale + bb.z) * L2E);
            float e3 = exp2f((sc[tmK][3] * scale + bb.w) * L2E);
            sc[tmK][0] = e0; sc[tmK][1] = e1;
            sc[tmK][2] = e2; sc[tmK][3] = e3;
            s += (e0 + e1) + (e2 + e3);
        }
        s += __shfl_xor(s, 16);
        s += __shfl_xor(s, 32);
        float rs = 1.0f / s;
        #pragma unroll
        for (int tmK = 0; tmK < 4; ++tmK)
            pP[tmK][tmQ] = pk4(sc[tmK][0] * rs, sc[tmK][1] * rs,
                               sc[tmK][2] * rs, sc[tmK][3] * rs);
    }

    // ---- PV: out[q][d] = sum_{tmK} mfma(A=pP[tmK][tmq], B=fV[tmK][tn]) ----
    // D[q 4lg+r][d lr] -> same coalesced float4 store as before.
    f32x4 o[4][2];
    #pragma unroll
    for (int tmq = 0; tmq < 4; ++tmq)
        #pragma unroll
        for (int tn = 0; tn < 2; ++tn)
            o[tmq][tn] = (f32x4){0.f, 0.f, 0.f, 0.f};
    #pragma unroll
    for (int tmK = 0; tmK < 4; ++tmK)
        #pragma unroll
        for (int tmq = 0; tmq < 4; ++tmq)
            #pragma unroll
            for (int tn = 0; tn < 2; ++tn)
                o[tmq][tn] = MFMA16(pP[tmK][tmq], fV[tmK][tn], o[tmq][tn]);

    // ---- direct coalesced float4 stores (4 consecutive tokens per reg) ----
    #pragma unroll
    for (int tmq = 0; tmq < 4; ++tmq)
        #pragma unroll
        for (int tn = 0; tn < 2; ++tn) {
            int ch = 32 * w + 16 * tn + lr;
            int tok = 16 * tmq + 4 * lg;
            float4 ov;
            ov.x = o[tmq][tn][0];
            ov.y = o[tmq][tn][1];
            ov.z = o[tmq][tn][2];
            ov.w = o[tmq][tn][3];
            *(float4*)(out + xbase + (long)ch * 16384 + tok) = ov;
        }
}

extern "C" void kernel_launch(void* const* d_in, const int* in_sizes, int n_in,
                              void* d_out, int out_size, void* d_ws, size_t ws_size,
                              hipStream_t stream) {
    const float* x  = (const float*)d_in[0];
    const float* Wq = (const float*)d_in[1];
    const float* bq = (const float*)d_in[2];
    const float* Wk = (const float*)d_in[3];
    const float* bk = (const float*)d_in[4];
    const float* Wv = (const float*)d_in[5];
    const float* bv = (const float*)d_in[6];
    const float* Bb = (const float*)d_in[7];
    float* out = (float*)d_out;
    ushort* wbf = (ushort*)d_ws;   // 3 x 128x128 bf16 = 96 KB

    wconv<<<64, 256, 0, stream>>>(Wq, Wk, Wv, wbf);
    attn_win<<<4096, 256, 0, stream>>>(x, wbf, bq, bk, bv, Bb, out);
}

// Round 18
// 112.313 us; speedup vs baseline: 1.7792x; 1.4472x over previous
//
#include <hip/hip_runtime.h>
#include <hip/hip_bf16.h>

// Windowed MHA, B=16 C=128 H=W=128, WINDOW=64, heads=4, d=32.
// R18 HYBRID: one wave = one (window, head); 4096 x 256thr; ONE barrier.
//  - Projections: K=32 MFMA + b128 loads (R15-proven; per-MFMA cost is flat
//    in K, so biggest K wins -- R17 lesson).
//  - Attention (QK^T, PV): K=16 MFMA (R17-proven) consuming the projection /
//    softmax D-layouts DIRECTLY -- the K=16 fragment k-map (4*lg+j) equals
//    the D-layout reg-map, so ALL shfl redistribution (~160 bpermute + 80
//    selects + serial chains in R13-R15) is gone.

typedef __attribute__((ext_vector_type(8))) short bf16x8;
typedef __attribute__((ext_vector_type(4))) short bf16x4;
typedef __attribute__((ext_vector_type(4))) float f32x4;

#define MFMA32(A, B, C) __builtin_amdgcn_mfma_f32_16x16x32_bf16((A), (B), (C), 0, 0, 0)
#define MFMA16(A, B, C) __builtin_amdgcn_mfma_f32_16x16x16bf16_1k((A), (B), (C), 0, 0, 0)

__device__ __forceinline__ ushort f2bf(float f) {
    __hip_bfloat16 h = __float2bfloat16(f);       // RNE
    ushort u; __builtin_memcpy(&u, &h, 2); return u;
}
__device__ __forceinline__ unsigned pk2(float a, float b) {
    __hip_bfloat162 h = __float22bfloat162_rn(make_float2(a, b));  // lo=a, hi=b
    unsigned u; __builtin_memcpy(&u, &h, 4); return u;
}
__device__ __forceinline__ bf16x4 pk4(float a, float b, float c, float d) {
    uint2 u; u.x = pk2(a, b); u.y = pk2(c, d);
    bf16x4 r; __builtin_memcpy(&r, &u, 8); return r;
}
// 256B-row tile (sX): row bits 0-3 ^ bits 4-5 -> byte bits 4-7.
__device__ __forceinline__ int fsw(int row) { return ((row ^ (row >> 4)) & 15) << 4; }

__global__ void wconv(const float* __restrict__ Wq, const float* __restrict__ Wk,
                      const float* __restrict__ Wv, ushort* __restrict__ out) {
    int i = blockIdx.x * 256 + threadIdx.x;        // 16384 per matrix
    out[i]         = f2bf(Wq[i]);
    out[16384 + i] = f2bf(Wk[i]);
    out[32768 + i] = f2bf(Wv[i]);
}

__global__ __launch_bounds__(256, 2)
void attn_win(const float* __restrict__ x, const ushort* __restrict__ wbf,
              const float* __restrict__ bq, const float* __restrict__ bk,
              const float* __restrict__ bv, const float* __restrict__ Bb,
              float* __restrict__ out) {
    __shared__ __align__(16) char sX[16384];   // the ONLY LDS tenant

    const int tid = threadIdx.x;
    const int w = tid >> 6;          // wave = head (0..3)
    const int l = tid & 63;
    const int lr = l & 15;
    const int lg = (l >> 4) & 3;
    const int blk = blockIdx.x;
    const int b = blk >> 8, n = blk & 255;
    const long xbase = (long)b * 128 * 16384 + n * 64;

    // ---- stage X: 4-channel quads -> packed uint2 ds_writes (2 per thread) ----
    #pragma unroll
    for (int it = 0; it < 2; ++it) {
        int idx = it * 256 + tid;            // 512 items: 32 cq x 16 t4
        int cq = idx >> 4, t4 = idx & 15;
        const float* px = x + xbase + (long)(4 * cq) * 16384 + t4 * 4;
        float4 v0 = *(const float4*)(px);
        float4 v1 = *(const float4*)(px + 16384);
        float4 v2 = *(const float4*)(px + 32768);
        float4 v3 = *(const float4*)(px + 49152);
        float a0[4] = {v0.x, v0.y, v0.z, v0.w};
        float a1[4] = {v1.x, v1.y, v1.z, v1.w};
        float a2[4] = {v2.x, v2.y, v2.z, v2.w};
        float a3[4] = {v3.x, v3.y, v3.z, v3.w};
        #pragma unroll
        for (int jj = 0; jj < 4; ++jj) {
            int t = t4 * 4 + jj;
            uint2 pk;
            pk.x = pk2(a0[jj], a1[jj]);
            pk.y = pk2(a2[jj], a3[jj]);
            *(uint2*)(sX + t * 256 + ((8 * cq) ^ fsw(t))) = pk;
        }
    }
    __syncthreads();   // THE ONLY BARRIER

    // ---- Q,K projections FUSED (W.X^T), K=32 MFMA, b128 loads (R15) ----
    // D[och 4lg+r][tok lr] per (tn,tm) -> pk4 -> K=16 fragment, k-slice tn.
    bf16x4 fQ[4][2], fK[4][2];   // [tm tok-tile][tn och-slice]
    {
        f32x4 accQ[2][4], accK[2][4];   // [tn][tm]
        #pragma unroll
        for (int tn = 0; tn < 2; ++tn) {
            float4 bbq = *(const float4*)(bq + 32 * w + 16 * tn + 4 * lg);
            float4 bbk = *(const float4*)(bk + 32 * w + 16 * tn + 4 * lg);
            #pragma unroll
            for (int tm = 0; tm < 4; ++tm) {
                accQ[tn][tm] = (f32x4){bbq.x, bbq.y, bbq.z, bbq.w};
                accK[tn][tm] = (f32x4){bbk.x, bbk.y, bbk.z, bbk.w};
            }
        }
        #pragma unroll
        for (int kk = 0; kk < 4; ++kk) {
            bf16x8 aXk[4];
            #pragma unroll
            for (int tm = 0; tm < 4; ++tm) {
                int row = 16 * tm + lr;
                aXk[tm] = *(const bf16x8*)(sX + row * 256
                              + (((8 * lg + 32 * kk) * 2) ^ fsw(row)));
            }
            bf16x8 bWq[2], bWk[2];
            #pragma unroll
            for (int tn = 0; tn < 2; ++tn) {
                int orow = (32 * w + 16 * tn + lr) * 128 + 8 * lg + 32 * kk;
                bWq[tn] = *(const bf16x8*)(wbf + orow);
                bWk[tn] = *(const bf16x8*)(wbf + 16384 + orow);
            }
            #pragma unroll
            for (int tn = 0; tn < 2; ++tn)
                #pragma unroll
                for (int tm = 0; tm < 4; ++tm) {
                    accQ[tn][tm] = MFMA32(bWq[tn], aXk[tm], accQ[tn][tm]);
                    accK[tn][tm] = MFMA32(bWk[tn], aXk[tm], accK[tn][tm]);
                }
        }
        #pragma unroll
        for (int tm = 0; tm < 4; ++tm)
            #pragma unroll
            for (int tn = 0; tn < 2; ++tn) {
                fQ[tm][tn] = pk4(accQ[tn][tm][0], accQ[tn][tm][1],
                                 accQ[tn][tm][2], accQ[tn][tm][3]);
                fK[tm][tn] = pk4(accK[tn][tm][0], accK[tn][tm][1],
                                 accK[tn][tm][2], accK[tn][tm][3]);
            }
    }

    // ---- V projection (X.W^T), K=32: D[tok 4lg+r][och lr] -> PV B-frags ----
    bf16x4 fV[4][2];   // [tmi key-slice][tn]
    {
        const ushort* wp = wbf + 32768;
        f32x4 accV[4][2];
        #pragma unroll
        for (int tn = 0; tn < 2; ++tn) {
            float bias = bv[32 * w + 16 * tn + lr];
            #pragma unroll
            for (int tmi = 0; tmi < 4; ++tmi)
                accV[tmi][tn] = (f32x4){bias, bias, bias, bias};
        }
        #pragma unroll
        for (int kk = 0; kk < 4; ++kk) {
            bf16x8 aXk[4];
            #pragma unroll
            for (int tmi = 0; tmi < 4; ++tmi) {
                int row = 16 * tmi + lr;
                aXk[tmi] = *(const bf16x8*)(sX + row * 256
                               + (((8 * lg + 32 * kk) * 2) ^ fsw(row)));
            }
            bf16x8 bW[2];
            #pragma unroll
            for (int tn = 0; tn < 2; ++tn)
                bW[tn] = *(const bf16x8*)(wp + (32 * w + 16 * tn + lr) * 128 + 8 * lg + 32 * kk);
            #pragma unroll
            for (int tmi = 0; tmi < 4; ++tmi)
                #pragma unroll
                for (int tn = 0; tn < 2; ++tn)
                    accV[tmi][tn] = MFMA32(aXk[tmi], bW[tn], accV[tmi][tn]);
        }
        #pragma unroll
        for (int tmi = 0; tmi < 4; ++tmi)
            #pragma unroll
            for (int tn = 0; tn < 2; ++tn)
                fV[tmi][tn] = pk4(accV[tmi][tn][0], accV[tmi][tn][1],
                                  accV[tmi][tn][2], accV[tmi][tn][3]);
    }

    // ---- per-tmQ: scores^T = K=16 mfma(A=fK, B=fQ) -> softmax -> pack P ----
    // D[k 16tmK+4lg+r][q 16tmQ+lr]; P pack is directly the PV A-fragment. (R17)
    const float scale = 0.17677669529663687f;   // 1/sqrt(32)
    const float L2E = 1.4426950408889634f;
    bf16x4 pP[4][4];   // [tmK][tmQ]
    #pragma unroll
    for (int tmQ = 0; tmQ < 4; ++tmQ) {
        f32x4 sc[4];
        #pragma unroll
        for (int tmK = 0; tmK < 4; ++tmK) {
            sc[tmK] = (f32x4){0.f, 0.f, 0.f, 0.f};
            sc[tmK] = MFMA16(fK[tmK][0], fQ[tmQ][0], sc[tmK]);
            sc[tmK] = MFMA16(fK[tmK][1], fQ[tmQ][1], sc[tmK]);
        }
        int q = 16 * tmQ + lr;
        float s = 0.f;
        #pragma unroll
        for (int tmK = 0; tmK < 4; ++tmK) {
            float4 bb = *(const float4*)(Bb + q * 64 + 16 * tmK + 4 * lg);
            float e0 = exp2f((sc[tmK][0] * scale + bb.x) * L2E);
            float e1 = exp2f((sc[tmK][1] * scale + bb.y) * L2E);
            float e2 = exp2f((sc[tmK][2] * scale + bb.z) * L2E);
            float e3 = exp2f((sc[tmK][3] * scale + bb.w) * L2E);
            sc[tmK][0] = e0; sc[tmK][1] = e1;
            sc[tmK][2] = e2; sc[tmK][3] = e3;
            s += (e0 + e1) + (e2 + e3);
        }
        s += __shfl_xor(s, 16);
        s += __shfl_xor(s, 32);
        float rs = 1.0f / s;
        #pragma unroll
        for (int tmK = 0; tmK < 4; ++tmK)
            pP[tmK][tmQ] = pk4(sc[tmK][0] * rs, sc[tmK][1] * rs,
                               sc[tmK][2] * rs, sc[tmK][3] * rs);
    }

    // ---- PV: K=16 mfma(A=pP, B=fV); D[q 4lg+r][d lr] (R17) ----
    f32x4 o[4][2];
    #pragma unroll
    for (int tmq = 0; tmq < 4; ++tmq)
        #pragma unroll
        for (int tn = 0; tn < 2; ++tn)
            o[tmq][tn] = (f32x4){0.f, 0.f, 0.f, 0.f};
    #pragma unroll
    for (int tmK = 0; tmK < 4; ++tmK)
        #pragma unroll
        for (int tmq = 0; tmq < 4; ++tmq)
            #pragma unroll
            for (int tn = 0; tn < 2; ++tn)
                o[tmq][tn] = MFMA16(pP[tmK][tmq], fV[tmK][tn], o[tmq][tn]);

    // ---- direct coalesced float4 stores (4 consecutive tokens per reg) ----
    #pragma unroll
    for (int tmq = 0; tmq < 4; ++tmq)
        #pragma unroll
        for (int tn = 0; tn < 2; ++tn) {
            int ch = 32 * w + 16 * tn + lr;
            int tok = 16 * tmq + 4 * lg;
            float4 ov;
            ov.x = o[tmq][tn][0];
            ov.y = o[tmq][tn][1];
            ov.z = o[tmq][tn][2];
            ov.w = o[tmq][tn][3];
            *(float4*)(out + xbase + (long)ch * 16384 + tok) = ov;
        }
}

extern "C" void kernel_launch(void* const* d_in, const int* in_sizes, int n_in,
                              void* d_out, int out_size, void* d_ws, size_t ws_size,
                              hipStream_t stream) {
    const float* x  = (const float*)d_in[0];
    const float* Wq = (const float*)d_in[1];
    const float* bq = (const float*)d_in[2];
    const float* Wk = (const float*)d_in[3];
    const float* bk = (const float*)d_in[4];
    const float* Wv = (const float*)d_in[5];
    const float* bv = (const float*)d_in[6];
    const float* Bb = (const float*)d_in[7];
    float* out = (float*)d_out;
    ushort* wbf = (ushort*)d_ws;   // 3 x 128x128 bf16 = 96 KB

    wconv<<<64, 256, 0, stream>>>(Wq, Wk, Wv, wbf);
    attn_win<<<4096, 256, 0, stream>>>(x, wbf, bq, bk, bv, Bb, out);
}